// Round 1
// baseline (268.983 us; speedup 1.0000x reference)
//
#include <hip/hip_runtime.h>

#define N_NODES 8192
#define DIM 32
#define NCLS 16
#define SPLITK 16
#define KSEG (N_NODES / SPLITK) /* 512 */

typedef __bf16 bf16x8 __attribute__((ext_vector_type(8)));
typedef float f32x4 __attribute__((ext_vector_type(4)));

__device__ inline unsigned short f2bf(float f) {
  unsigned u = __float_as_uint(f);
  u = u + 0x7FFFu + ((u >> 16) & 1u);  // round-to-nearest-even
  return (unsigned short)(u >> 16);
}

__device__ inline float artanh_pos(float x) {  // x >= 0, clipped like jnp reference
  x = fminf(x, 1.0f - 1e-7f);
  return 0.5f * logf((1.0f + x) / (1.0f - x));
}

// ---------------- A fp32 -> bf16 (RNE) ----------------
__global__ void k_convert(const float* __restrict__ A, unsigned short* __restrict__ Abf) {
  const size_t total = (size_t)N_NODES * N_NODES;
  size_t i = ((size_t)blockIdx.x * blockDim.x + threadIdx.x) * 8;
  const size_t stride = (size_t)gridDim.x * blockDim.x * 8;
  for (; i < total; i += stride) {
    float4 v0 = *(const float4*)(A + i);
    float4 v1 = *(const float4*)(A + i + 4);
    uint4 o;
    o.x = f2bf(v0.x) | ((unsigned)f2bf(v0.y) << 16);
    o.y = f2bf(v0.z) | ((unsigned)f2bf(v0.w) << 16);
    o.z = f2bf(v1.x) | ((unsigned)f2bf(v1.y) << 16);
    o.w = f2bf(v1.z) | ((unsigned)f2bf(v1.w) << 16);
    *(uint4*)(Abf + i) = o;
  }
}

// ---------------- pre: mobius_matvec + gamma, writes G^T bf16 [48][N] ----------------
// cols 0..31 = gamma*XW, col 32 = gamma-1, col 33 = 1 (rowsum->alpha), 34..47 = 0
__global__ void k_pre(const float* __restrict__ X, const float* __restrict__ W,
                      unsigned short* __restrict__ GT) {
  __shared__ float Wl[DIM * DIM];
  for (int i = threadIdx.x; i < DIM * DIM; i += blockDim.x) Wl[i] = W[i];
  __syncthreads();
  const int n = blockIdx.x * blockDim.x + threadIdx.x;
  float x[DIM];
#pragma unroll
  for (int i = 0; i < DIM; i += 4) {
    float4 v = *(const float4*)(X + (size_t)n * DIM + i);
    x[i] = v.x; x[i + 1] = v.y; x[i + 2] = v.z; x[i + 3] = v.w;
  }
  float xn2 = 0.f;
#pragma unroll
  for (int i = 0; i < DIM; i++) xn2 += x[i] * x[i];
  float xn = sqrtf(fmaxf(xn2, 1e-30f));
  float mx[DIM];
#pragma unroll
  for (int j = 0; j < DIM; j++) mx[j] = 0.f;
  for (int i = 0; i < DIM; i++) {
    float xi = x[i];
#pragma unroll
    for (int j = 0; j < DIM; j++) mx[j] = fmaf(xi, Wl[i * DIM + j], mx[j]);
  }
  float mxn2 = 0.f;
#pragma unroll
  for (int j = 0; j < DIM; j++) mxn2 += mx[j] * mx[j];
  float mxn = sqrtf(fmaxf(mxn2, 1e-30f));
  float t = tanhf(mxn / xn * artanh_pos(xn));
  float sc = t / mxn;
  float xw[DIM];
  float x2n = 0.f;
#pragma unroll
  for (int j = 0; j < DIM; j++) { xw[j] = sc * mx[j]; x2n += xw[j] * xw[j]; }
  float gamma = 2.0f / fmaxf(1.0f - x2n, 1e-15f);
#pragma unroll
  for (int c = 0; c < DIM; c++) GT[(size_t)c * N_NODES + n] = f2bf(gamma * xw[c]);
  GT[(size_t)DIM * N_NODES + n] = f2bf(gamma - 1.0f);
  GT[(size_t)(DIM + 1) * N_NODES + n] = f2bf(1.0f);
#pragma unroll
  for (int c = DIM + 2; c < 48; c++) GT[(size_t)c * N_NODES + n] = 0;
}

// ---------------- MFMA matmul: Cpart[split] = A_bf16[rows, kseg] @ BT^T ----------------
// per wave: 32 rows x NF*16 cols; direct per-lane global frag loads, no LDS.
template <int NF>
__global__ __launch_bounds__(256) void k_mm(const unsigned short* __restrict__ A,
                                            const unsigned short* __restrict__ BT,
                                            float* __restrict__ Cpart) {
  const int lane = threadIdx.x & 63;
  const int wid = threadIdx.x >> 6;
  const int r0 = blockIdx.x * 128 + wid * 32;
  const int k0 = blockIdx.y * KSEG;
  const int lr = lane & 15;
  const int lk = (lane >> 4) * 8;
  f32x4 acc[2][NF];
#pragma unroll
  for (int m = 0; m < 2; m++)
#pragma unroll
    for (int nf = 0; nf < NF; nf++) acc[m][nf] = (f32x4){0.f, 0.f, 0.f, 0.f};
  const unsigned short* pa0 = A + (size_t)(r0 + lr) * N_NODES + k0 + lk;
  const unsigned short* pa1 = pa0 + (size_t)16 * N_NODES;
  const unsigned short* pb[NF];
#pragma unroll
  for (int nf = 0; nf < NF; nf++) pb[nf] = BT + (size_t)(nf * 16 + lr) * N_NODES + k0 + lk;
#pragma unroll 4
  for (int kk = 0; kk < KSEG; kk += 32) {
    bf16x8 a0 = *(const bf16x8*)(pa0 + kk);
    bf16x8 a1 = *(const bf16x8*)(pa1 + kk);
#pragma unroll
    for (int nf = 0; nf < NF; nf++) {
      bf16x8 b = *(const bf16x8*)(pb[nf] + kk);
      acc[0][nf] = __builtin_amdgcn_mfma_f32_16x16x32_bf16(a0, b, acc[0][nf], 0, 0, 0);
      acc[1][nf] = __builtin_amdgcn_mfma_f32_16x16x32_bf16(a1, b, acc[1][nf], 0, 0, 0);
    }
  }
  const int NCOL = NF * 16;
  float* Cb = Cpart + (size_t)blockIdx.y * N_NODES * NCOL;
#pragma unroll
  for (int m = 0; m < 2; m++)
#pragma unroll
    for (int nf = 0; nf < NF; nf++) {
      if (NF == 3 && nf == 2 && lr >= 4) continue;  // cols 36..47 are zero, never read
#pragma unroll
      for (int j = 0; j < 4; j++) {
        int row = r0 + m * 16 + (lane >> 4) * 4 + j;
        int col = nf * 16 + lr;
        Cb[(size_t)row * NCOL + col] = acc[m][nf][j];
      }
    }
}

// ---------------- post: splitK reduce + gyromidpoint + scalar-mul + sigma ----------------
__global__ void k_post(const float* __restrict__ Cpart, float* __restrict__ Xout) {
  const int n = blockIdx.x * blockDim.x + threadIdx.x;
  float acc[36];
#pragma unroll
  for (int c = 0; c < 36; c++) acc[c] = 0.f;
  for (int s = 0; s < SPLITK; s++) {
    const float4* p = (const float4*)(Cpart + ((size_t)s * N_NODES + n) * 48);
#pragma unroll
    for (int q = 0; q < 9; q++) {
      float4 v = p[q];
      acc[q * 4 + 0] += v.x; acc[q * 4 + 1] += v.y;
      acc[q * 4 + 2] += v.z; acc[q * 4 + 3] += v.w;
    }
  }
  float denom = acc[32];
  float alpha = acc[33];
  denom = (denom >= 0.f) ? fmaxf(denom, 1e-10f) : fminf(denom, -1e-10f);
  float inv = 1.0f / denom;
  float v[DIM];
  float vn2 = 0.f;
#pragma unroll
  for (int c = 0; c < DIM; c++) { v[c] = acc[c] * inv; vn2 += v[c] * v[c]; }
  float vn = sqrtf(fmaxf(vn2, 1e-30f));
  // mobius_scalar_mul(alpha, mobius_scalar_mul(0.5, v)) then logmap0:
  // u = alpha*0.5*artanh(vn) * v/vn  (direction preserved, alpha > 0)
  float un = alpha * 0.5f * artanh_pos(vn);
  float su = un / vn;
  float r[DIM];
  float rn2 = 0.f;
#pragma unroll
  for (int c = 0; c < DIM; c++) { r[c] = fmaxf(su * v[c], 0.f); rn2 += r[c] * r[c]; }
  float rn = sqrtf(fmaxf(rn2, 1e-30f));
  float so = tanhf(rn) / rn;  // expmap0
#pragma unroll
  for (int c = 0; c < DIM; c += 4) {
    float4 o = {so * r[c], so * r[c + 1], so * r[c + 2], so * r[c + 3]};
    *(float4*)(Xout + (size_t)n * DIM + c) = o;
  }
}

// ---------------- logits: hyperbolic MLR, writes logits^T bf16 [16][N] ----------------
__global__ void k_logits(const float* __restrict__ X, const float* __restrict__ Wl_g,
                         const float* __restrict__ B_g, unsigned short* __restrict__ LT) {
  __shared__ float Wc[DIM * NCLS];  // [d][c]
  __shared__ float Bc[NCLS * DIM];  // [c][d]
  __shared__ float an_s[NCLS], lam_s[NCLS], b2_s[NCLS];
  for (int i = threadIdx.x; i < DIM * NCLS; i += blockDim.x) { Wc[i] = Wl_g[i]; Bc[i] = B_g[i]; }
  __syncthreads();
  if (threadIdx.x < NCLS) {
    int c = threadIdx.x;
    float b2 = 0.f, w2 = 0.f;
    for (int d = 0; d < DIM; d++) {
      b2 += Bc[c * DIM + d] * Bc[c * DIM + d];
      w2 += Wc[d * NCLS + c] * Wc[d * NCLS + c];
    }
    b2_s[c] = b2;
    an_s[c] = fmaxf(sqrtf(w2), 1e-10f);
    lam_s[c] = 2.0f / fmaxf(1.0f - b2, 1e-15f);
  }
  __syncthreads();
  const int n = blockIdx.x * blockDim.x + threadIdx.x;
  float x[DIM];
  float y2 = 0.f;
#pragma unroll
  for (int i = 0; i < DIM; i += 4) {
    float4 vv = *(const float4*)(X + (size_t)n * DIM + i);
    x[i] = vv.x; x[i + 1] = vv.y; x[i + 2] = vv.z; x[i + 3] = vv.w;
  }
#pragma unroll
  for (int i = 0; i < DIM; i++) y2 += x[i] * x[i];
  for (int c = 0; c < NCLS; c++) {
    float b2 = b2_s[c];
    float bx = 0.f;
    for (int d = 0; d < DIM; d++) bx += Bc[c * DIM + d] * x[d];
    float xy = -bx;  // dot(-b, x)
    float f1 = 1.0f + 2.0f * xy + y2;
    float f2 = 1.0f - b2;
    float den = fmaxf(1.0f + 2.0f * xy + b2 * y2, 1e-15f);
    float invden = 1.0f / den;
    float zn2 = 0.f, za = 0.f;
    for (int d = 0; d < DIM; d++) {
      float z = (f1 * (-Bc[c * DIM + d]) + f2 * x[d]) * invden;
      zn2 += z * z;
      za += z * Wc[d * NCLS + c];
    }
    float zn = fmaxf(sqrtf(fmaxf(zn2, 1e-30f)), 1e-10f);
    float dist = asinhf(2.0f * za / ((1.0f - zn * zn) * an_s[c]));
    LT[(size_t)c * N_NODES + n] = f2bf(lam_s[c] * an_s[c] * dist);
  }
}

// ---------------- final splitK reduce into d_out ----------------
__global__ void k_reduce_out(const float* __restrict__ Opart, float* __restrict__ out) {
  const int total = N_NODES * NCLS;
  int i = blockIdx.x * blockDim.x + threadIdx.x;
  if (i < total) {
    float s = 0.f;
    for (int q = 0; q < SPLITK; q++) s += Opart[(size_t)q * total + i];
    out[i] = s;
  }
}

extern "C" void kernel_launch(void* const* d_in, const int* in_sizes, int n_in,
                              void* d_out, int out_size, void* d_ws, size_t ws_size,
                              hipStream_t stream) {
  (void)in_sizes; (void)n_in; (void)out_size; (void)ws_size;
  const float* X  = (const float*)d_in[0];
  const float* A  = (const float*)d_in[1];
  const float* W1 = (const float*)d_in[2];
  const float* W2 = (const float*)d_in[3];
  const float* WL = (const float*)d_in[4];
  const float* PK = (const float*)d_in[5];
  float* out = (float*)d_out;

  char* ws = (char*)d_ws;
  unsigned short* Abf = (unsigned short*)ws;                           // 134,217,728 B
  unsigned short* GT  = (unsigned short*)(ws + 134217728);             //     786,432 B
  float* Xbuf         = (float*)(ws + 134217728 + 786432);             //   1,048,576 B
  float* Cpart        = (float*)(ws + 134217728 + 786432 + 1048576);   //  25,165,824 B
  unsigned short* LT  = (unsigned short*)(ws + 134217728 + 786432 + 1048576 + 25165824);
  float* Opart = Cpart;  // reuse: Cpart dead after k_post of layer 2

  k_convert<<<4096, 256, 0, stream>>>(A, Abf);

  // layer 1
  k_pre<<<N_NODES / 64, 64, 0, stream>>>(X, W1, GT);
  k_mm<3><<<dim3(64, SPLITK), 256, 0, stream>>>(Abf, GT, Cpart);
  k_post<<<N_NODES / 64, 64, 0, stream>>>(Cpart, Xbuf);

  // layer 2
  k_pre<<<N_NODES / 64, 64, 0, stream>>>(Xbuf, W2, GT);
  k_mm<3><<<dim3(64, SPLITK), 256, 0, stream>>>(Abf, GT, Cpart);
  k_post<<<N_NODES / 64, 64, 0, stream>>>(Cpart, Xbuf);

  // logits + aggregation
  k_logits<<<N_NODES / 64, 64, 0, stream>>>(Xbuf, WL, PK, LT);
  k_mm<1><<<dim3(64, SPLITK), 256, 0, stream>>>(Abf, LT, Opart);
  k_reduce_out<<<(N_NODES * NCLS) / 256, 256, 0, stream>>>(Opart, out);
}

// Round 2
// 251.030 us; speedup vs baseline: 1.0715x; 1.0715x over previous
//
#include <hip/hip_runtime.h>

#define N_NODES 8192
#define DIM 32
#define NCLS 16
#define SPLITK 8
#define KSEG (N_NODES / SPLITK) /* 1024 */

typedef __bf16 bf16x8 __attribute__((ext_vector_type(8)));
typedef float f32x4 __attribute__((ext_vector_type(4)));

__device__ inline unsigned short f2bf(float f) {
  unsigned u = __float_as_uint(f);
  u = u + 0x7FFFu + ((u >> 16) & 1u);  // round-to-nearest-even
  return (unsigned short)(u >> 16);
}

__device__ inline float artanh_pos(float x) {  // x >= 0, clipped like jnp reference
  x = fminf(x, 1.0f - 1e-7f);
  return 0.5f * logf((1.0f + x) / (1.0f - x));
}

__device__ inline bf16x8 cvt8(float4 lo, float4 hi) {
  bf16x8 r;
  r[0] = (__bf16)lo.x; r[1] = (__bf16)lo.y; r[2] = (__bf16)lo.z; r[3] = (__bf16)lo.w;
  r[4] = (__bf16)hi.x; r[5] = (__bf16)hi.y; r[6] = (__bf16)hi.z; r[7] = (__bf16)hi.w;
  return r;
}

// ---------------- pre (layer 1): mobius_matvec + gamma -> G^T bf16 [48][N] ----------------
// cols 0..31 = gamma*XW, col 32 = gamma-1, col 33 = 1 (rowsum->alpha), 34..47 = 0
__device__ inline void pre_math(const float* __restrict__ Wl, const float x[DIM],
                                unsigned short* __restrict__ GT, int n) {
  float xn2 = 0.f;
#pragma unroll
  for (int i = 0; i < DIM; i++) xn2 += x[i] * x[i];
  float xn = sqrtf(fmaxf(xn2, 1e-30f));
  float mx[DIM];
#pragma unroll
  for (int j = 0; j < DIM; j++) mx[j] = 0.f;
  for (int i = 0; i < DIM; i++) {
    float xi = x[i];
#pragma unroll
    for (int j = 0; j < DIM; j++) mx[j] = fmaf(xi, Wl[i * DIM + j], mx[j]);
  }
  float mxn2 = 0.f;
#pragma unroll
  for (int j = 0; j < DIM; j++) mxn2 += mx[j] * mx[j];
  float mxn = sqrtf(fmaxf(mxn2, 1e-30f));
  float t = tanhf(mxn / xn * artanh_pos(xn));
  float sc = t / mxn;
  float xw[DIM];
  float x2n = 0.f;
#pragma unroll
  for (int j = 0; j < DIM; j++) { xw[j] = sc * mx[j]; x2n += xw[j] * xw[j]; }
  float gamma = 2.0f / fmaxf(1.0f - x2n, 1e-15f);
#pragma unroll
  for (int c = 0; c < DIM; c++) GT[(size_t)c * N_NODES + n] = f2bf(gamma * xw[c]);
  GT[(size_t)DIM * N_NODES + n] = f2bf(gamma - 1.0f);
  GT[(size_t)(DIM + 1) * N_NODES + n] = f2bf(1.0f);
#pragma unroll
  for (int c = DIM + 2; c < 48; c++) GT[(size_t)c * N_NODES + n] = 0;
}

__global__ void k_pre1(const float* __restrict__ X, const float* __restrict__ W,
                       unsigned short* __restrict__ GT) {
  __shared__ float Wl[DIM * DIM];
  for (int i = threadIdx.x; i < DIM * DIM; i += blockDim.x) Wl[i] = W[i];
  __syncthreads();
  const int n = blockIdx.x * blockDim.x + threadIdx.x;
  float x[DIM];
#pragma unroll
  for (int i = 0; i < DIM; i += 4) {
    float4 v = *(const float4*)(X + (size_t)n * DIM + i);
    x[i] = v.x; x[i + 1] = v.y; x[i + 2] = v.z; x[i + 3] = v.w;
  }
  pre_math(Wl, x, GT, n);
}

// ---------------- shared post math: splitK reduce + gyromidpoint + lincomb + sigma ----------------
__device__ inline void post_math(const float* __restrict__ Cpart, int n, float xo[DIM]) {
  float acc[36];
#pragma unroll
  for (int c = 0; c < 36; c++) acc[c] = 0.f;
  for (int s = 0; s < SPLITK; s++) {
    const float4* p = (const float4*)(Cpart + ((size_t)s * N_NODES + n) * 48);
#pragma unroll
    for (int q = 0; q < 9; q++) {
      float4 v = p[q];
      acc[q * 4 + 0] += v.x; acc[q * 4 + 1] += v.y;
      acc[q * 4 + 2] += v.z; acc[q * 4 + 3] += v.w;
    }
  }
  float denom = acc[32];
  float alpha = acc[33];
  denom = (denom >= 0.f) ? fmaxf(denom, 1e-10f) : fminf(denom, -1e-10f);
  float inv = 1.0f / denom;
  float v[DIM];
  float vn2 = 0.f;
#pragma unroll
  for (int c = 0; c < DIM; c++) { v[c] = acc[c] * inv; vn2 += v[c] * v[c]; }
  float vn = sqrtf(fmaxf(vn2, 1e-30f));
  // mobius_scalar_mul(alpha, mobius_scalar_mul(0.5, v)) then logmap0 -> relu -> expmap0
  float un = alpha * 0.5f * artanh_pos(vn);
  float su = un / vn;
  float r[DIM];
  float rn2 = 0.f;
#pragma unroll
  for (int c = 0; c < DIM; c++) { r[c] = fmaxf(su * v[c], 0.f); rn2 += r[c] * r[c]; }
  float rn = sqrtf(fmaxf(rn2, 1e-30f));
  float so = tanhf(rn) / rn;
#pragma unroll
  for (int c = 0; c < DIM; c++) xo[c] = so * r[c];
}

// ---------------- fused post(layer1) + pre(layer2) ----------------
__global__ void k_postpre(const float* __restrict__ Cpart, const float* __restrict__ W,
                          unsigned short* __restrict__ GT) {
  __shared__ float Wl[DIM * DIM];
  for (int i = threadIdx.x; i < DIM * DIM; i += blockDim.x) Wl[i] = W[i];
  __syncthreads();
  const int n = blockIdx.x * blockDim.x + threadIdx.x;
  float x[DIM];
  post_math(Cpart, n, x);
  pre_math(Wl, x, GT, n);
}

// ---------------- fused post(layer2) + hyperbolic MLR logits -> logits^T bf16 [16][N] ----------------
__global__ void k_postlogits(const float* __restrict__ Cpart, const float* __restrict__ Wl_g,
                             const float* __restrict__ B_g, unsigned short* __restrict__ LT) {
  __shared__ float Wc[DIM * NCLS];  // [d][c]
  __shared__ float Bc[NCLS * DIM];  // [c][d]
  __shared__ float an_s[NCLS], lam_s[NCLS], b2_s[NCLS];
  for (int i = threadIdx.x; i < DIM * NCLS; i += blockDim.x) { Wc[i] = Wl_g[i]; Bc[i] = B_g[i]; }
  __syncthreads();
  if (threadIdx.x < NCLS) {
    int c = threadIdx.x;
    float b2 = 0.f, w2 = 0.f;
    for (int d = 0; d < DIM; d++) {
      b2 += Bc[c * DIM + d] * Bc[c * DIM + d];
      w2 += Wc[d * NCLS + c] * Wc[d * NCLS + c];
    }
    b2_s[c] = b2;
    an_s[c] = fmaxf(sqrtf(w2), 1e-10f);
    lam_s[c] = 2.0f / fmaxf(1.0f - b2, 1e-15f);
  }
  __syncthreads();
  const int n = blockIdx.x * blockDim.x + threadIdx.x;
  float x[DIM];
  post_math(Cpart, n, x);
  float y2 = 0.f;
#pragma unroll
  for (int i = 0; i < DIM; i++) y2 += x[i] * x[i];
  for (int c = 0; c < NCLS; c++) {
    float b2 = b2_s[c];
    float bx = 0.f;
    for (int d = 0; d < DIM; d++) bx += Bc[c * DIM + d] * x[d];
    float xy = -bx;  // dot(-b, x)
    float f1 = 1.0f + 2.0f * xy + y2;
    float f2 = 1.0f - b2;
    float den = fmaxf(1.0f + 2.0f * xy + b2 * y2, 1e-15f);
    float invden = 1.0f / den;
    float zn2 = 0.f, za = 0.f;
    for (int d = 0; d < DIM; d++) {
      float z = (f1 * (-Bc[c * DIM + d]) + f2 * x[d]) * invden;
      zn2 += z * z;
      za += z * Wc[d * NCLS + c];
    }
    float zn = fmaxf(sqrtf(fmaxf(zn2, 1e-30f)), 1e-10f);
    float dist = asinhf(2.0f * za / ((1.0f - zn * zn) * an_s[c]));
    LT[(size_t)c * N_NODES + n] = f2bf(lam_s[c] * an_s[c] * dist);
  }
}

// ---------------- MFMA matmul pass 1, fused with fp32->bf16 convert of A ----------------
// Reads A fp32, converts in-register (feeds MFMA + writes Abf bf16 for passes 2/3).
__global__ __launch_bounds__(256) void k_mm_conv(const float* __restrict__ A,
                                                 const unsigned short* __restrict__ BT,
                                                 float* __restrict__ Cpart,
                                                 unsigned short* __restrict__ Abf) {
  const int lane = threadIdx.x & 63;
  const int wid = threadIdx.x >> 6;
  const int r0 = blockIdx.x * 128 + wid * 32;
  const int k0 = blockIdx.y * KSEG;
  const int lr = lane & 15;
  const int lk = (lane >> 4) * 8;
  f32x4 acc[2][3];
#pragma unroll
  for (int m = 0; m < 2; m++)
#pragma unroll
    for (int nf = 0; nf < 3; nf++) acc[m][nf] = (f32x4){0.f, 0.f, 0.f, 0.f};
  const float* pa0 = A + (size_t)(r0 + lr) * N_NODES + k0 + lk;
  const float* pa1 = pa0 + (size_t)16 * N_NODES;
  unsigned short* sa0 = Abf + (size_t)(r0 + lr) * N_NODES + k0 + lk;
  unsigned short* sa1 = sa0 + (size_t)16 * N_NODES;
  const unsigned short* pb[3];
#pragma unroll
  for (int nf = 0; nf < 3; nf++) pb[nf] = BT + (size_t)(nf * 16 + lr) * N_NODES + k0 + lk;
#pragma unroll 2
  for (int kk = 0; kk < KSEG; kk += 32) {
    float4 a0lo = *(const float4*)(pa0 + kk);
    float4 a0hi = *(const float4*)(pa0 + kk + 4);
    float4 a1lo = *(const float4*)(pa1 + kk);
    float4 a1hi = *(const float4*)(pa1 + kk + 4);
    bf16x8 a0 = cvt8(a0lo, a0hi);
    bf16x8 a1 = cvt8(a1lo, a1hi);
    *(bf16x8*)(sa0 + kk) = a0;
    *(bf16x8*)(sa1 + kk) = a1;
#pragma unroll
    for (int nf = 0; nf < 3; nf++) {
      bf16x8 b = *(const bf16x8*)(pb[nf] + kk);
      acc[0][nf] = __builtin_amdgcn_mfma_f32_16x16x32_bf16(a0, b, acc[0][nf], 0, 0, 0);
      acc[1][nf] = __builtin_amdgcn_mfma_f32_16x16x32_bf16(a1, b, acc[1][nf], 0, 0, 0);
    }
  }
  float* Cb = Cpart + (size_t)blockIdx.y * N_NODES * 48;
#pragma unroll
  for (int m = 0; m < 2; m++)
#pragma unroll
    for (int nf = 0; nf < 3; nf++) {
      if (nf == 2 && lr >= 4) continue;  // cols 36..47 are zero, never read
#pragma unroll
      for (int j = 0; j < 4; j++) {
        int row = r0 + m * 16 + (lane >> 4) * 4 + j;
        int col = nf * 16 + lr;
        Cb[(size_t)row * 48 + col] = acc[m][nf][j];
      }
    }
}

// ---------------- MFMA matmul (bf16 A): Cpart[split] = A[rows, kseg] @ BT^T ----------------
template <int NF>
__global__ __launch_bounds__(256) void k_mm(const unsigned short* __restrict__ A,
                                            const unsigned short* __restrict__ BT,
                                            float* __restrict__ Cpart) {
  const int lane = threadIdx.x & 63;
  const int wid = threadIdx.x >> 6;
  const int r0 = blockIdx.x * 128 + wid * 32;
  const int k0 = blockIdx.y * KSEG;
  const int lr = lane & 15;
  const int lk = (lane >> 4) * 8;
  f32x4 acc[2][NF];
#pragma unroll
  for (int m = 0; m < 2; m++)
#pragma unroll
    for (int nf = 0; nf < NF; nf++) acc[m][nf] = (f32x4){0.f, 0.f, 0.f, 0.f};
  const unsigned short* pa0 = A + (size_t)(r0 + lr) * N_NODES + k0 + lk;
  const unsigned short* pa1 = pa0 + (size_t)16 * N_NODES;
  const unsigned short* pb[NF];
#pragma unroll
  for (int nf = 0; nf < NF; nf++) pb[nf] = BT + (size_t)(nf * 16 + lr) * N_NODES + k0 + lk;
#pragma unroll 4
  for (int kk = 0; kk < KSEG; kk += 32) {
    bf16x8 a0 = *(const bf16x8*)(pa0 + kk);
    bf16x8 a1 = *(const bf16x8*)(pa1 + kk);
#pragma unroll
    for (int nf = 0; nf < NF; nf++) {
      bf16x8 b = *(const bf16x8*)(pb[nf] + kk);
      acc[0][nf] = __builtin_amdgcn_mfma_f32_16x16x32_bf16(a0, b, acc[0][nf], 0, 0, 0);
      acc[1][nf] = __builtin_amdgcn_mfma_f32_16x16x32_bf16(a1, b, acc[1][nf], 0, 0, 0);
    }
  }
  const int NCOL = NF * 16;
  float* Cb = Cpart + (size_t)blockIdx.y * N_NODES * NCOL;
#pragma unroll
  for (int m = 0; m < 2; m++)
#pragma unroll
    for (int nf = 0; nf < NF; nf++) {
      if (NF == 3 && nf == 2 && lr >= 4) continue;
#pragma unroll
      for (int j = 0; j < 4; j++) {
        int row = r0 + m * 16 + (lane >> 4) * 4 + j;
        int col = nf * 16 + lr;
        Cb[(size_t)row * NCOL + col] = acc[m][nf][j];
      }
    }
}

// ---------------- final splitK reduce into d_out ----------------
__global__ void k_reduce_out(const float* __restrict__ Opart, float* __restrict__ out) {
  const int total = N_NODES * NCLS;
  int i = blockIdx.x * blockDim.x + threadIdx.x;
  if (i < total) {
    float s = 0.f;
    for (int q = 0; q < SPLITK; q++) s += Opart[(size_t)q * total + i];
    out[i] = s;
  }
}

extern "C" void kernel_launch(void* const* d_in, const int* in_sizes, int n_in,
                              void* d_out, int out_size, void* d_ws, size_t ws_size,
                              hipStream_t stream) {
  (void)in_sizes; (void)n_in; (void)out_size; (void)ws_size;
  const float* X  = (const float*)d_in[0];
  const float* A  = (const float*)d_in[1];
  const float* W1 = (const float*)d_in[2];
  const float* W2 = (const float*)d_in[3];
  const float* WL = (const float*)d_in[4];
  const float* PK = (const float*)d_in[5];
  float* out = (float*)d_out;

  char* ws = (char*)d_ws;
  unsigned short* Abf = (unsigned short*)ws;                    // 134,217,728 B
  unsigned short* GT  = (unsigned short*)(ws + 134217728);      //     786,432 B
  float* Cpart        = (float*)(ws + 134217728 + 786432);      //  12,582,912 B (SPLITK=8)
  unsigned short* LT  = (unsigned short*)(ws + 134217728 + 786432 + 12582912);
  float* Opart = Cpart;  // reuse: Cpart dead after k_postlogits

  // layer 1 (A convert fused into the matmul)
  k_pre1<<<N_NODES / 64, 64, 0, stream>>>(X, W1, GT);
  k_mm_conv<<<dim3(64, SPLITK), 256, 0, stream>>>(A, GT, Cpart, Abf);
  k_postpre<<<N_NODES / 64, 64, 0, stream>>>(Cpart, W2, GT);

  // layer 2
  k_mm<3><<<dim3(64, SPLITK), 256, 0, stream>>>(Abf, GT, Cpart);
  k_postlogits<<<N_NODES / 64, 64, 0, stream>>>(Cpart, WL, PK, LT);

  // logits aggregation
  k_mm<1><<<dim3(64, SPLITK), 256, 0, stream>>>(Abf, LT, Opart);
  k_reduce_out<<<(N_NODES * NCLS + 255) / 256, 256, 0, stream>>>(Opart, out);
}

// Round 3
// 248.204 us; speedup vs baseline: 1.0837x; 1.0114x over previous
//
#include <hip/hip_runtime.h>

#define N_NODES 8192
#define DIM 32
#define NCLS 16
#define SPLITK 32
#define KSEG (N_NODES / SPLITK) /* 256 */
#define NCOLC 36                /* packed partial-C columns (cols 36..47 are structurally zero) */

typedef __bf16 bf16x8 __attribute__((ext_vector_type(8)));
typedef float f32x4 __attribute__((ext_vector_type(4)));

__device__ inline unsigned short f2bf(float f) {
  unsigned u = __float_as_uint(f);
  u = u + 0x7FFFu + ((u >> 16) & 1u);  // round-to-nearest-even
  return (unsigned short)(u >> 16);
}

__device__ inline float artanh_pos(float x) {  // x >= 0, clipped like jnp reference
  x = fminf(x, 1.0f - 1e-7f);
  return 0.5f * logf((1.0f + x) / (1.0f - x));
}

__device__ inline bf16x8 cvt8(float4 lo, float4 hi) {
  bf16x8 r;
  r[0] = (__bf16)lo.x; r[1] = (__bf16)lo.y; r[2] = (__bf16)lo.z; r[3] = (__bf16)lo.w;
  r[4] = (__bf16)hi.x; r[5] = (__bf16)hi.y; r[6] = (__bf16)hi.z; r[7] = (__bf16)hi.w;
  return r;
}

// ---------------- pre: mobius_matvec + gamma -> G^T bf16 [48][N] ----------------
// cols 0..31 = gamma*XW, col 32 = gamma-1, col 33 = 1 (rowsum->alpha), 34..47 = 0
__device__ inline void pre_math(const float* __restrict__ Wl, const float x[DIM],
                                unsigned short* __restrict__ GT, int n) {
  float xn2 = 0.f;
#pragma unroll
  for (int i = 0; i < DIM; i++) xn2 += x[i] * x[i];
  float xn = sqrtf(fmaxf(xn2, 1e-30f));
  float mx[DIM];
#pragma unroll
  for (int j = 0; j < DIM; j++) mx[j] = 0.f;
  for (int i = 0; i < DIM; i++) {
    float xi = x[i];
#pragma unroll
    for (int j = 0; j < DIM; j++) mx[j] = fmaf(xi, Wl[i * DIM + j], mx[j]);
  }
  float mxn2 = 0.f;
#pragma unroll
  for (int j = 0; j < DIM; j++) mxn2 += mx[j] * mx[j];
  float mxn = sqrtf(fmaxf(mxn2, 1e-30f));
  float t = tanhf(mxn / xn * artanh_pos(xn));
  float sc = t / mxn;
  float xw[DIM];
  float x2n = 0.f;
#pragma unroll
  for (int j = 0; j < DIM; j++) { xw[j] = sc * mx[j]; x2n += xw[j] * xw[j]; }
  float gamma = 2.0f / fmaxf(1.0f - x2n, 1e-15f);
#pragma unroll
  for (int c = 0; c < DIM; c++) GT[(size_t)c * N_NODES + n] = f2bf(gamma * xw[c]);
  GT[(size_t)DIM * N_NODES + n] = f2bf(gamma - 1.0f);
  GT[(size_t)(DIM + 1) * N_NODES + n] = f2bf(1.0f);
#pragma unroll
  for (int c = DIM + 2; c < 48; c++) GT[(size_t)c * N_NODES + n] = 0;
}

__global__ void k_pre1(const float* __restrict__ X, const float* __restrict__ W,
                       unsigned short* __restrict__ GT) {
  __shared__ float Wl[DIM * DIM];
  for (int i = threadIdx.x; i < DIM * DIM; i += blockDim.x) Wl[i] = W[i];
  __syncthreads();
  const int n = blockIdx.x * blockDim.x + threadIdx.x;
  float x[DIM];
#pragma unroll
  for (int i = 0; i < DIM; i += 4) {
    float4 v = *(const float4*)(X + (size_t)n * DIM + i);
    x[i] = v.x; x[i + 1] = v.y; x[i + 2] = v.z; x[i + 3] = v.w;
  }
  pre_math(Wl, x, GT, n);
}

// ---------------- shared post math: splitK reduce + gyromidpoint + lincomb + sigma ----------------
__device__ inline void post_math(const float* __restrict__ Cpart, int n, float xo[DIM]) {
  float acc[NCOLC];
#pragma unroll
  for (int c = 0; c < NCOLC; c++) acc[c] = 0.f;
  for (int s = 0; s < SPLITK; s++) {
    const float4* p = (const float4*)(Cpart + ((size_t)s * N_NODES + n) * NCOLC);
#pragma unroll
    for (int q = 0; q < NCOLC / 4; q++) {
      float4 v = p[q];
      acc[q * 4 + 0] += v.x; acc[q * 4 + 1] += v.y;
      acc[q * 4 + 2] += v.z; acc[q * 4 + 3] += v.w;
    }
  }
  float denom = acc[32];
  float alpha = acc[33];
  denom = (denom >= 0.f) ? fmaxf(denom, 1e-10f) : fminf(denom, -1e-10f);
  float inv = 1.0f / denom;
  float v[DIM];
  float vn2 = 0.f;
#pragma unroll
  for (int c = 0; c < DIM; c++) { v[c] = acc[c] * inv; vn2 += v[c] * v[c]; }
  float vn = sqrtf(fmaxf(vn2, 1e-30f));
  // mobius_scalar_mul(alpha, mobius_scalar_mul(0.5, v)) then logmap0 -> relu -> expmap0
  float un = alpha * 0.5f * artanh_pos(vn);
  float su = un / vn;
  float r[DIM];
  float rn2 = 0.f;
#pragma unroll
  for (int c = 0; c < DIM; c++) { r[c] = fmaxf(su * v[c], 0.f); rn2 += r[c] * r[c]; }
  float rn = sqrtf(fmaxf(rn2, 1e-30f));
  float so = tanhf(rn) / rn;
#pragma unroll
  for (int c = 0; c < DIM; c++) xo[c] = so * r[c];
}

// ---------------- fused post(layer1) + pre(layer2) ----------------
__global__ void k_postpre(const float* __restrict__ Cpart, const float* __restrict__ W,
                          unsigned short* __restrict__ GT) {
  __shared__ float Wl[DIM * DIM];
  for (int i = threadIdx.x; i < DIM * DIM; i += blockDim.x) Wl[i] = W[i];
  __syncthreads();
  const int n = blockIdx.x * blockDim.x + threadIdx.x;
  float x[DIM];
  post_math(Cpart, n, x);
  pre_math(Wl, x, GT, n);
}

// ---------------- fused post(layer2) + hyperbolic MLR logits -> logits^T bf16 [16][N] ----------------
__global__ void k_postlogits(const float* __restrict__ Cpart, const float* __restrict__ Wl_g,
                             const float* __restrict__ B_g, unsigned short* __restrict__ LT) {
  __shared__ float Wc[DIM * NCLS];  // [d][c]
  __shared__ float Bc[NCLS * DIM];  // [c][d]
  __shared__ float an_s[NCLS], lam_s[NCLS], b2_s[NCLS];
  for (int i = threadIdx.x; i < DIM * NCLS; i += blockDim.x) { Wc[i] = Wl_g[i]; Bc[i] = B_g[i]; }
  __syncthreads();
  if (threadIdx.x < NCLS) {
    int c = threadIdx.x;
    float b2 = 0.f, w2 = 0.f;
    for (int d = 0; d < DIM; d++) {
      b2 += Bc[c * DIM + d] * Bc[c * DIM + d];
      w2 += Wc[d * NCLS + c] * Wc[d * NCLS + c];
    }
    b2_s[c] = b2;
    an_s[c] = fmaxf(sqrtf(w2), 1e-10f);
    lam_s[c] = 2.0f / fmaxf(1.0f - b2, 1e-15f);
  }
  __syncthreads();
  const int n = blockIdx.x * blockDim.x + threadIdx.x;
  float x[DIM];
  post_math(Cpart, n, x);
  float y2 = 0.f;
#pragma unroll
  for (int i = 0; i < DIM; i++) y2 += x[i] * x[i];
  for (int c = 0; c < NCLS; c++) {
    float b2 = b2_s[c];
    float bx = 0.f;
    for (int d = 0; d < DIM; d++) bx += Bc[c * DIM + d] * x[d];
    float xy = -bx;  // dot(-b, x)
    float f1 = 1.0f + 2.0f * xy + y2;
    float f2 = 1.0f - b2;
    float den = fmaxf(1.0f + 2.0f * xy + b2 * y2, 1e-15f);
    float invden = 1.0f / den;
    float zn2 = 0.f, za = 0.f;
    for (int d = 0; d < DIM; d++) {
      float z = (f1 * (-Bc[c * DIM + d]) + f2 * x[d]) * invden;
      zn2 += z * z;
      za += z * Wc[d * NCLS + c];
    }
    float zn = fmaxf(sqrtf(fmaxf(zn2, 1e-30f)), 1e-10f);
    float dist = asinhf(2.0f * za / ((1.0f - zn * zn) * an_s[c]));
    LT[(size_t)c * N_NODES + n] = f2bf(lam_s[c] * an_s[c] * dist);
  }
}

// ---------------- MFMA matmul pass 1, fused with fp32->bf16 convert of A ----------------
__global__ __launch_bounds__(256) void k_mm_conv(const float* __restrict__ A,
                                                 const unsigned short* __restrict__ BT,
                                                 float* __restrict__ Cpart,
                                                 unsigned short* __restrict__ Abf) {
  const int lane = threadIdx.x & 63;
  const int wid = threadIdx.x >> 6;
  const int r0 = blockIdx.x * 128 + wid * 32;
  const int k0 = blockIdx.y * KSEG;
  const int lr = lane & 15;
  const int lk = (lane >> 4) * 8;
  f32x4 acc[2][3];
#pragma unroll
  for (int m = 0; m < 2; m++)
#pragma unroll
    for (int nf = 0; nf < 3; nf++) acc[m][nf] = (f32x4){0.f, 0.f, 0.f, 0.f};
  const float* pa0 = A + (size_t)(r0 + lr) * N_NODES + k0 + lk;
  const float* pa1 = pa0 + (size_t)16 * N_NODES;
  unsigned short* sa0 = Abf + (size_t)(r0 + lr) * N_NODES + k0 + lk;
  unsigned short* sa1 = sa0 + (size_t)16 * N_NODES;
  const unsigned short* pb[3];
#pragma unroll
  for (int nf = 0; nf < 3; nf++) pb[nf] = BT + (size_t)(nf * 16 + lr) * N_NODES + k0 + lk;
#pragma unroll 2
  for (int kk = 0; kk < KSEG; kk += 32) {
    float4 a0lo = *(const float4*)(pa0 + kk);
    float4 a0hi = *(const float4*)(pa0 + kk + 4);
    float4 a1lo = *(const float4*)(pa1 + kk);
    float4 a1hi = *(const float4*)(pa1 + kk + 4);
    bf16x8 a0 = cvt8(a0lo, a0hi);
    bf16x8 a1 = cvt8(a1lo, a1hi);
    *(bf16x8*)(sa0 + kk) = a0;
    *(bf16x8*)(sa1 + kk) = a1;
#pragma unroll
    for (int nf = 0; nf < 3; nf++) {
      bf16x8 b = *(const bf16x8*)(pb[nf] + kk);
      acc[0][nf] = __builtin_amdgcn_mfma_f32_16x16x32_bf16(a0, b, acc[0][nf], 0, 0, 0);
      acc[1][nf] = __builtin_amdgcn_mfma_f32_16x16x32_bf16(a1, b, acc[1][nf], 0, 0, 0);
    }
  }
  float* Cb = Cpart + (size_t)blockIdx.y * N_NODES * NCOLC;
#pragma unroll
  for (int m = 0; m < 2; m++)
#pragma unroll
    for (int nf = 0; nf < 3; nf++) {
      if (nf == 2 && lr >= 4) continue;  // cols 36..47 are zero, never read
#pragma unroll
      for (int j = 0; j < 4; j++) {
        int row = r0 + m * 16 + (lane >> 4) * 4 + j;
        int col = nf * 16 + lr;
        Cb[(size_t)row * NCOLC + col] = acc[m][nf][j];
      }
    }
}

// ---------------- MFMA matmul (bf16 A): Cpart[split] = A[rows, kseg] @ BT^T ----------------
template <int NF>
__global__ __launch_bounds__(256) void k_mm(const unsigned short* __restrict__ A,
                                            const unsigned short* __restrict__ BT,
                                            float* __restrict__ Cpart) {
  const int lane = threadIdx.x & 63;
  const int wid = threadIdx.x >> 6;
  const int r0 = blockIdx.x * 128 + wid * 32;
  const int k0 = blockIdx.y * KSEG;
  const int lr = lane & 15;
  const int lk = (lane >> 4) * 8;
  f32x4 acc[2][NF];
#pragma unroll
  for (int m = 0; m < 2; m++)
#pragma unroll
    for (int nf = 0; nf < NF; nf++) acc[m][nf] = (f32x4){0.f, 0.f, 0.f, 0.f};
  const unsigned short* pa0 = A + (size_t)(r0 + lr) * N_NODES + k0 + lk;
  const unsigned short* pa1 = pa0 + (size_t)16 * N_NODES;
  const unsigned short* pb[NF];
#pragma unroll
  for (int nf = 0; nf < NF; nf++) pb[nf] = BT + (size_t)(nf * 16 + lr) * N_NODES + k0 + lk;
#pragma unroll 4
  for (int kk = 0; kk < KSEG; kk += 32) {
    bf16x8 a0 = *(const bf16x8*)(pa0 + kk);
    bf16x8 a1 = *(const bf16x8*)(pa1 + kk);
#pragma unroll
    for (int nf = 0; nf < NF; nf++) {
      bf16x8 b = *(const bf16x8*)(pb[nf] + kk);
      acc[0][nf] = __builtin_amdgcn_mfma_f32_16x16x32_bf16(a0, b, acc[0][nf], 0, 0, 0);
      acc[1][nf] = __builtin_amdgcn_mfma_f32_16x16x32_bf16(a1, b, acc[1][nf], 0, 0, 0);
    }
  }
  const int NCOL = (NF == 3) ? NCOLC : NF * 16;
  float* Cb = Cpart + (size_t)blockIdx.y * N_NODES * NCOL;
#pragma unroll
  for (int m = 0; m < 2; m++)
#pragma unroll
    for (int nf = 0; nf < NF; nf++) {
      if (NF == 3 && nf == 2 && lr >= 4) continue;
#pragma unroll
      for (int j = 0; j < 4; j++) {
        int row = r0 + m * 16 + (lane >> 4) * 4 + j;
        int col = nf * 16 + lr;
        Cb[(size_t)row * NCOL + col] = acc[m][nf][j];
      }
    }
}

// ---------------- final splitK reduce into d_out ----------------
__global__ void k_reduce_out(const float* __restrict__ Opart, float* __restrict__ out) {
  const int total = N_NODES * NCLS;
  int i = blockIdx.x * blockDim.x + threadIdx.x;
  if (i < total) {
    float s = 0.f;
    for (int q = 0; q < SPLITK; q++) s += Opart[(size_t)q * total + i];
    out[i] = s;
  }
}

extern "C" void kernel_launch(void* const* d_in, const int* in_sizes, int n_in,
                              void* d_out, int out_size, void* d_ws, size_t ws_size,
                              hipStream_t stream) {
  (void)in_sizes; (void)n_in; (void)out_size; (void)ws_size;
  const float* X  = (const float*)d_in[0];
  const float* A  = (const float*)d_in[1];
  const float* W1 = (const float*)d_in[2];
  const float* W2 = (const float*)d_in[3];
  const float* WL = (const float*)d_in[4];
  const float* PK = (const float*)d_in[5];
  float* out = (float*)d_out;

  char* ws = (char*)d_ws;
  unsigned short* Abf = (unsigned short*)ws;                    // 134,217,728 B
  unsigned short* GT  = (unsigned short*)(ws + 134217728);      //     786,432 B
  float* Cpart        = (float*)(ws + 134217728 + 786432);      //  37,748,736 B (SPLITK=32, 36 cols)
  unsigned short* LT  = (unsigned short*)(ws + 134217728 + 786432 + 37748736);
  float* Opart = Cpart;  // reuse: Cpart dead after k_postlogits

  // layer 1 (A convert fused into the matmul)
  k_pre1<<<N_NODES / 64, 64, 0, stream>>>(X, W1, GT);
  k_mm_conv<<<dim3(64, SPLITK), 256, 0, stream>>>(A, GT, Cpart, Abf);
  k_postpre<<<N_NODES / 64, 64, 0, stream>>>(Cpart, W2, GT);

  // layer 2
  k_mm<3><<<dim3(64, SPLITK), 256, 0, stream>>>(Abf, GT, Cpart);
  k_postlogits<<<N_NODES / 64, 64, 0, stream>>>(Cpart, WL, PK, LT);

  // logits aggregation
  k_mm<1><<<dim3(64, SPLITK), 256, 0, stream>>>(Abf, LT, Opart);
  k_reduce_out<<<(N_NODES * NCLS + 255) / 256, 256, 0, stream>>>(Opart, out);
}